// Round 24
// baseline (476.064 us; speedup 1.0000x reference)
//
#include <hip/hip_runtime.h>

#define E_NUM 12000
#define D_DIM 6272
#define H_DIM 256
#define M1 24000

typedef __attribute__((ext_vector_type(8))) short short8;
typedef __attribute__((ext_vector_type(8))) __bf16 bf16x8;
typedef __attribute__((ext_vector_type(4))) float f32x4;

__device__ __forceinline__ float silu_f(float x) {
  return x / (1.0f + __expf(-x));
}

__device__ __forceinline__ bf16x8 ld_frag(const short* p) {
  return __builtin_bit_cast(bf16x8, *(const short8*)p);
}

__device__ __forceinline__ bf16x8 cvt8(f32x4 a, f32x4 b) {
  bf16x8 r;
#pragma unroll
  for (int j = 0; j < 4; ++j) {
    r[j] = (__bf16)a[j];
    r[4 + j] = (__bf16)b[j];
  }
  return r;
}

__device__ __forceinline__ void gll16(const void* g, void* l) {
  __builtin_amdgcn_global_load_lds(
      (const __attribute__((address_space(1))) void*)g,
      (__attribute__((address_space(3))) void*)l, 16, 0, 0);
}

// ---- fused pack (champion, verbatim): blocks [0,196) W1->P1; [196,392) W2->P2 ----
__global__ void pack_both(const float* __restrict__ W1, short* __restrict__ P1,
                          const float* __restrict__ W2, short* __restrict__ P2) {
  const int bid = blockIdx.x;
  const int t = threadIdx.x;
  if (bid < 196) {
    const int kt = bid;
    const int col = t;
    const float* src = W1 + (size_t)kt * 32 * H_DIM + col;
    short* dst = P1 + ((size_t)kt * H_DIM + col) * 32;
#pragma unroll
    for (int c = 0; c < 4; ++c) {
      short8 s;
#pragma unroll
      for (int j = 0; j < 8; ++j)
        s[j] = __builtin_bit_cast(short, (__bf16)src[(size_t)(c * 8 + j) * H_DIM]);
      *(short8*)(dst + c * 8) = s;
    }
  } else {
    const int b = bid - 196;
    const int kt = (b / 49) * 2 + (t >> 7);
    const int col = (b % 49) * 128 + (t & 127);
    const float* src = W2 + (size_t)kt * 32 * D_DIM + col;
    short* dst = P2 + ((size_t)kt * D_DIM + col) * 32;
#pragma unroll
    for (int c = 0; c < 4; ++c) {
      short8 s;
#pragma unroll
      for (int j = 0; j < 8; ++j)
        s[j] = __builtin_bit_cast(short, (__bf16)src[(size_t)(c * 8 + j) * D_DIM]);
      *(short8*)(dst + c * 8) = s;
    }
  }
}

// ====== GEMM1 v16b: BM=64, 512 thr / 8 waves — STRADDLE FIXED (per-row src select) ======
// Halves total B L2 traffic (2.35 GB -> 1.17 GB) at constant 12 waves/CU.
// Block 187 spans the node_embed/ori boundary at row 12000 -> each staging row
// picks its source independently. Swizzle invariant: row&7 = (t>>5)&7 (16r = 0 mod 8).
#define G1_NT 49
__launch_bounds__(512, 2)
__global__ void gemm1_kernel(const float* __restrict__ node_embed,
                             const float* __restrict__ ori,
                             const float* __restrict__ x_edge_c,
                             const short* __restrict__ P1,
                             const float* __restrict__ b1,
                             short* __restrict__ hgp) {
  __shared__ __align__(16) float Abuf[2][64 * 128];  // 2 x 32 KB

  const int t = threadIdx.x;   // 0..511
  const int wave = t >> 6;
  const int wm = wave >> 2;    // 0..1 : 32-row half
  const int wnn = wave & 3;    // 0..3 : 64-col quarter
  const int lane = t & 63;
  const int l15 = lane & 15;
  const int lq = lane >> 4;
  const int m_base = blockIdx.x * 64;

  // staging: round r (0..3): dest float idx = t*4 + r*2048 -> row (t>>5)+16r, chunk t&31.
  // PER-ROW source select (straddle fix); logical chunk = (t&24)|((t&7)^((t>>5)&7)).
  const int srow = t >> 5;
  const int soff = ((t & 24) | ((t & 7) ^ (srow & 7))) * 4;
  const float* aR[4];
#pragma unroll
  for (int rr = 0; rr < 4; ++rr) {
    const int grow = m_base + srow + 16 * rr;
    const float* base = (grow < E_NUM) ? (node_embed + (size_t)grow * D_DIM)
                                       : (ori + (size_t)(grow - E_NUM) * D_DIM);
    aR[rr] = base + soff;
  }

  // B fragment base: col = wnn*64 + n*16 + l15, k-slot lq*8 -> 1KB contiguous frags
  const short* bbase = P1 + (size_t)(wnn * 64 + l15) * 32 + lq * 8;

  const int asw = l15 & 7;

  f32x4 acc[2][4];
#pragma unroll
  for (int m = 0; m < 2; ++m)
#pragma unroll
    for (int n = 0; n < 4; ++n) acc[m][n] = (f32x4){0.f, 0.f, 0.f, 0.f};

#define G1_STAGE(IT, BUF)                                       \
  do {                                                          \
    gll16(aR[0] + (size_t)(IT)*128, &Abuf[BUF][t * 4]);         \
    gll16(aR[1] + (size_t)(IT)*128, &Abuf[BUF][t * 4 + 2048]);  \
    gll16(aR[2] + (size_t)(IT)*128, &Abuf[BUF][t * 4 + 4096]);  \
    gll16(aR[3] + (size_t)(IT)*128, &Abuf[BUF][t * 4 + 6144]);  \
  } while (0)

  G1_STAGE(0, 0);
  __syncthreads();

  int cur = 0;
  for (int it = 0; it < G1_NT; ++it) {
    const int nxt = cur ^ 1;

    // B frags for this mega-step: 4 kt-tiles x 4 n (1KB contiguous each, L2)
    bf16x8 bq[4][4];
    {
      const short* bs = bbase + (size_t)it * 32768;
#pragma unroll
      for (int ks = 0; ks < 4; ++ks)
#pragma unroll
        for (int n = 0; n < 4; ++n) bq[ks][n] = ld_frag(bs + ks * 8192 + n * 512);
    }

    if (it + 1 < G1_NT) G1_STAGE(it + 1, nxt);

    const float* Ap = &Abuf[cur][0];
#pragma unroll
    for (int ks = 0; ks < 4; ++ks) {
      bf16x8 af[2];
#pragma unroll
      for (int m = 0; m < 2; ++m) {
        const int row = wm * 32 + m * 16 + l15;
        const int c_lo = 8 * ks + 2 * lq;
        const int pl = (c_lo & 24) | ((c_lo & 7) ^ asw);
        const int ph = (c_lo & 24) | (((c_lo + 1) & 7) ^ asw);
        f32x4 lo = *(const f32x4*)(Ap + row * 128 + pl * 4);
        f32x4 hi = *(const f32x4*)(Ap + row * 128 + ph * 4);
        af[m] = cvt8(lo, hi);
      }
#pragma unroll
      for (int m = 0; m < 2; ++m)
#pragma unroll
        for (int n = 0; n < 4; ++n)
          acc[m][n] = __builtin_amdgcn_mfma_f32_16x16x32_bf16(af[m], bq[ks][n],
                                                              acc[m][n], 0, 0, 0);
    }
    __syncthreads();
    cur = nxt;
  }

  // epilogue: bias + silu + gate -> hgp panel layout [8][24000][32]
#pragma unroll
  for (int n = 0; n < 4; ++n) {
    const int col = wnn * 64 + n * 16 + l15;
    const float b1v = b1[col];
    const int panel = wnn * 2 + (n >> 1);
    const int cin = (n & 1) * 16 + l15;
#pragma unroll
    for (int m = 0; m < 2; ++m) {
#pragma unroll
      for (int i = 0; i < 4; ++i) {
        const int gmr = m_base + wm * 32 + m * 16 + lq * 4 + i;
        const int e = (gmr < E_NUM) ? gmr : gmr - E_NUM;
        float v = acc[m][n][i] + b1v;
        v = silu_f(v) * x_edge_c[(size_t)e * H_DIM + col];
        hgp[((size_t)panel * M1 + gmr) * 32 + cin] = __builtin_bit_cast(short, (__bf16)v);
      }
    }
  }
#undef G1_STAGE
}

// ====== GEMM2 v5 + T1 XCD swizzle (champion, verbatim) ======
#define G2_NWG (49 * 188)  // 9212
__launch_bounds__(256, 3)
__global__ void gemm2_kernel(const short* __restrict__ hgp,
                             const short* __restrict__ P2,
                             const float* __restrict__ b2,
                             float* __restrict__ out) {
  __shared__ __align__(16) short Als[2][128 * 64];  // 2 x 16 KB

  const int orig = blockIdx.x;
  const int xcd = orig & 7;
  const int idx = orig >> 3;
  const int q = G2_NWG >> 3;  // 1151
  const int r = G2_NWG & 7;   // 4
  const int wgid = (xcd < r ? xcd * (q + 1) : r * (q + 1) + (xcd - r) * q) + idx;
  const int d0 = (wgid % 49) * 128;
  const int e0 = (wgid / 49) * 64;

  const int t = threadIdx.x;
  const int wave = t >> 6;
  const int lane = t & 63;
  const int l15 = lane & 15;
  const int lq = lane >> 4;
  const int wr = wave >> 1;
  const int wc = wave & 1;

  const int R0 = t >> 3;
  const int cst = t & 7;
  const int cl = cst ^ (R0 & 7);
  const short* asrc[4];
#pragma unroll
  for (int rr = 0; rr < 4; ++rr) {
    int er = e0 + R0 + (rr & 1) * 32;
    if (er >= E_NUM) er = E_NUM - 1;
    const int grow = er + (rr >> 1) * E_NUM;
    asrc[rr] = hgp + (size_t)(cl >> 2) * (M1 * 32) + (size_t)grow * 32 + (cl & 3) * 8;
  }

  const short* bbase = P2 + (size_t)(d0 + wc * 64 + l15) * 32 + lq * 8;
  const int asw = l15 & 7;

  f32x4 acc[2][2][4];
#pragma unroll
  for (int h = 0; h < 2; ++h)
#pragma unroll
    for (int m = 0; m < 2; ++m)
#pragma unroll
      for (int n = 0; n < 4; ++n) acc[h][m][n] = (f32x4){0.f, 0.f, 0.f, 0.f};

#pragma unroll
  for (int rr = 0; rr < 4; ++rr) gll16(asrc[rr], &Als[0][t * 8 + rr * 2048]);
  __syncthreads();

  int cur = 0;
#pragma unroll
  for (int it = 0; it < 4; ++it) {
    const int nxt = cur ^ 1;
    if (it < 3) {
      const size_t ko = (size_t)(it + 1) * 2 * (M1 * 32);
#pragma unroll
      for (int rr = 0; rr < 4; ++rr) gll16(asrc[rr] + ko, &Als[nxt][t * 8 + rr * 2048]);
    }
    bf16x8 bq[2][4];
#pragma unroll
    for (int ks = 0; ks < 2; ++ks)
#pragma unroll
      for (int n = 0; n < 4; ++n)
        bq[ks][n] = ld_frag(bbase + (size_t)(it * 2 + ks) * (D_DIM * 32) + n * 512);

    bf16x8 af[2][2][2];
#pragma unroll
    for (int h = 0; h < 2; ++h)
#pragma unroll
      for (int m = 0; m < 2; ++m)
#pragma unroll
        for (int ks = 0; ks < 2; ++ks) {
          const int R = h * 64 + wr * 32 + m * 16 + l15;
          af[h][m][ks] = ld_frag(&Als[cur][R * 64 + (((ks * 4 + lq) ^ asw) * 8)]);
        }
#pragma unroll
    for (int ks = 0; ks < 2; ++ks)
#pragma unroll
      for (int h = 0; h < 2; ++h)
#pragma unroll
        for (int m = 0; m < 2; ++m)
#pragma unroll
          for (int n = 0; n < 4; ++n)
            acc[h][m][n] = __builtin_amdgcn_mfma_f32_16x16x32_bf16(
                af[h][m][ks], bq[ks][n], acc[h][m][n], 0, 0, 0);
    __syncthreads();
    cur = nxt;
  }

#pragma unroll
  for (int n = 0; n < 4; ++n) {
    const int col = d0 + wc * 64 + n * 16 + l15;
    const float b2v = b2[col];
#pragma unroll
    for (int m = 0; m < 2; ++m) {
#pragma unroll
      for (int i = 0; i < 4; ++i) {
        const int e = e0 + wr * 32 + m * 16 + lq * 4 + i;
        if (e < E_NUM) {
          out[(size_t)e * D_DIM + col] =
              silu_f(acc[0][m][n][i] + b2v) + silu_f(acc[1][m][n][i] + b2v);
        }
      }
    }
  }
}

extern "C" void kernel_launch(void* const* d_in, const int* in_sizes, int n_in,
                              void* d_out, int out_size, void* d_ws, size_t ws_size,
                              hipStream_t stream) {
  const float* node_embed = (const float*)d_in[0];
  const float* x_edge_c = (const float*)d_in[1];
  const float* ori = (const float*)d_in[2];
  const float* W1 = (const float*)d_in[3];
  const float* b1 = (const float*)d_in[4];
  const float* W2 = (const float*)d_in[5];
  const float* b2 = (const float*)d_in[6];
  float* out_p = (float*)d_out;

  char* ws = (char*)d_ws;
  short* P1 = (short*)ws;                   // [196][256][32] bf16 = 3,211,264 B
  short* P2 = (short*)(ws + 3211264);       // [8][6272][32] bf16 = 3,211,264 B
  short* hgp = (short*)(ws + 2 * 3211264);  // [8][24000][32] bf16 = 12,288,000 B

  pack_both<<<dim3(392), 256, 0, stream>>>(W1, P1, W2, P2);

  gemm1_kernel<<<dim3(M1 / 64), 512, 0, stream>>>(node_embed, ori, x_edge_c, P1, b1, hgp);

  gemm2_kernel<<<dim3(G2_NWG), 256, 0, stream>>>(hgp, P2, b2, out_p);
}

// Round 25
// 418.461 us; speedup vs baseline: 1.1377x; 1.1377x over previous
//
#include <hip/hip_runtime.h>

#define E_NUM 12000
#define D_DIM 6272
#define H_DIM 256
#define M1 24000

typedef __attribute__((ext_vector_type(8))) short short8;
typedef __attribute__((ext_vector_type(8))) __bf16 bf16x8;
typedef __attribute__((ext_vector_type(4))) float f32x4;

__device__ __forceinline__ float silu_f(float x) {
  return x / (1.0f + __expf(-x));
}

__device__ __forceinline__ bf16x8 ld_frag(const short* p) {
  return __builtin_bit_cast(bf16x8, *(const short8*)p);
}

__device__ __forceinline__ bf16x8 cvt8(f32x4 a, f32x4 b) {
  bf16x8 r;
#pragma unroll
  for (int j = 0; j < 4; ++j) {
    r[j] = (__bf16)a[j];
    r[4 + j] = (__bf16)b[j];
  }
  return r;
}

__device__ __forceinline__ void gll16(const void* g, void* l) {
  __builtin_amdgcn_global_load_lds(
      (const __attribute__((address_space(1))) void*)g,
      (__attribute__((address_space(3))) void*)l, 16, 0, 0);
}

// ---- fused pack (champion): blocks [0,196) W1->P1; [196,392) W2->P2 ----
__global__ void pack_both(const float* __restrict__ W1, short* __restrict__ P1,
                          const float* __restrict__ W2, short* __restrict__ P2) {
  const int bid = blockIdx.x;
  const int t = threadIdx.x;
  if (bid < 196) {
    const int kt = bid;
    const int col = t;
    const float* src = W1 + (size_t)kt * 32 * H_DIM + col;
    short* dst = P1 + ((size_t)kt * H_DIM + col) * 32;
#pragma unroll
    for (int c = 0; c < 4; ++c) {
      short8 s;
#pragma unroll
      for (int j = 0; j < 8; ++j)
        s[j] = __builtin_bit_cast(short, (__bf16)src[(size_t)(c * 8 + j) * H_DIM]);
      *(short8*)(dst + c * 8) = s;
    }
  } else {
    const int b = bid - 196;
    const int kt = (b / 49) * 2 + (t >> 7);
    const int col = (b % 49) * 128 + (t & 127);
    const float* src = W2 + (size_t)kt * 32 * D_DIM + col;
    short* dst = P2 + ((size_t)kt * D_DIM + col) * 32;
#pragma unroll
    for (int c = 0; c < 4; ++c) {
      short8 s;
#pragma unroll
      for (int j = 0; j < 8; ++j)
        s[j] = __builtin_bit_cast(short, (__bf16)src[(size_t)(c * 8 + j) * D_DIM]);
      *(short8*)(dst + c * 8) = s;
    }
  }
}

// ====== GEMM1 v13 (champion, verbatim): BM=32, BN=256, BK=128, 49 barriers ======
#define G1_NT 49
__launch_bounds__(256, 3)
__global__ void gemm1_kernel(const float* __restrict__ node_embed,
                             const float* __restrict__ ori,
                             const float* __restrict__ x_edge_c,
                             const short* __restrict__ P1,
                             const float* __restrict__ b1,
                             short* __restrict__ hgp) {
  __shared__ __align__(16) float Abuf[2][32 * 128];  // 2 x 16 KB

  const int t = threadIdx.x;
  const int wn = t >> 6;
  const int lane = t & 63;
  const int l15 = lane & 15;
  const int lq = lane >> 4;
  const int m_base = blockIdx.x * 32;

  const float* xb = (m_base < E_NUM) ? (node_embed + (size_t)m_base * D_DIM)
                                     : (ori + (size_t)(m_base - E_NUM) * D_DIM);

  // staging: round r (0..3): dest float idx = t*4 + r*1024 -> row (t>>5)+8r, chunk t&31.
  // logical chunk = (t&24) | ((t&7)^(t>>5));  (row&7 == t>>5 for all rounds)
  const float* aP =
      xb + (size_t)(t >> 5) * D_DIM + (((t & 24) | ((t & 7) ^ (t >> 5))) * 4);

  // B fragment base: col = wn*64 + n*16 + l15, k-slot lq*8 -> 1KB contiguous frags
  const short* bbase = P1 + (size_t)(wn * 64 + l15) * 32 + lq * 8;

  const int asw = l15 & 7;

  f32x4 acc[2][4];
#pragma unroll
  for (int m = 0; m < 2; ++m)
#pragma unroll
    for (int n = 0; n < 4; ++n) acc[m][n] = (f32x4){0.f, 0.f, 0.f, 0.f};

#define G1_STAGE(IT, BUF)                                                     \
  do {                                                                        \
    const float* _a = aP + (size_t)(IT)*128;                                  \
    gll16(_a, &Abuf[BUF][t * 4]);                                             \
    gll16(_a + (size_t)8 * D_DIM, &Abuf[BUF][t * 4 + 1024]);                  \
    gll16(_a + (size_t)16 * D_DIM, &Abuf[BUF][t * 4 + 2048]);                 \
    gll16(_a + (size_t)24 * D_DIM, &Abuf[BUF][t * 4 + 3072]);                 \
  } while (0)

  G1_STAGE(0, 0);
  __syncthreads();

  int cur = 0;
  for (int it = 0; it < G1_NT; ++it) {
    const int nxt = cur ^ 1;

    // B frags for this mega-step: 4 kt-tiles x 4 n (1KB contiguous each, L2)
    bf16x8 bq[4][4];
    {
      const short* bs = bbase + (size_t)it * 32768;
#pragma unroll
      for (int ks = 0; ks < 4; ++ks)
#pragma unroll
        for (int n = 0; n < 4; ++n) bq[ks][n] = ld_frag(bs + ks * 8192 + n * 512);
    }

    if (it + 1 < G1_NT) G1_STAGE(it + 1, nxt);

    const float* Ap = &Abuf[cur][0];
#pragma unroll
    for (int ks = 0; ks < 4; ++ks) {
      bf16x8 af[2];
#pragma unroll
      for (int m = 0; m < 2; ++m) {
        const int row = m * 16 + l15;
        const int c_lo = 8 * ks + 2 * lq;
        const int pl = (c_lo & 24) | ((c_lo & 7) ^ asw);
        const int ph = (c_lo & 24) | (((c_lo + 1) & 7) ^ asw);
        f32x4 lo = *(const f32x4*)(Ap + row * 128 + pl * 4);
        f32x4 hi = *(const f32x4*)(Ap + row * 128 + ph * 4);
        af[m] = cvt8(lo, hi);
      }
#pragma unroll
      for (int m = 0; m < 2; ++m)
#pragma unroll
        for (int n = 0; n < 4; ++n)
          acc[m][n] = __builtin_amdgcn_mfma_f32_16x16x32_bf16(af[m], bq[ks][n],
                                                              acc[m][n], 0, 0, 0);
    }
    __syncthreads();
    cur = nxt;
  }

  // epilogue: bias + silu + gate -> hgp panel layout [8][24000][32]
#pragma unroll
  for (int n = 0; n < 4; ++n) {
    const int col = wn * 64 + n * 16 + l15;
    const float b1v = b1[col];
    const int panel = wn * 2 + (n >> 1);
    const int cin = (n & 1) * 16 + l15;
#pragma unroll
    for (int m = 0; m < 2; ++m) {
#pragma unroll
      for (int i = 0; i < 4; ++i) {
        const int gmr = m_base + m * 16 + lq * 4 + i;
        const int e = (gmr < E_NUM) ? gmr : gmr - E_NUM;
        float v = acc[m][n][i] + b1v;
        v = silu_f(v) * x_edge_c[(size_t)e * H_DIM + col];
        hgp[((size_t)panel * M1 + gmr) * 32 + cin] = __builtin_bit_cast(short, (__bf16)v);
      }
    }
  }
#undef G1_STAGE
}

// ====== GEMM2 v5 + T1 XCD swizzle (champion, verbatim) ======
#define G2_NWG (49 * 188)  // 9212
__launch_bounds__(256, 3)
__global__ void gemm2_kernel(const short* __restrict__ hgp,
                             const short* __restrict__ P2,
                             const float* __restrict__ b2,
                             float* __restrict__ out) {
  __shared__ __align__(16) short Als[2][128 * 64];  // 2 x 16 KB

  const int orig = blockIdx.x;
  const int xcd = orig & 7;
  const int idx = orig >> 3;
  const int q = G2_NWG >> 3;  // 1151
  const int r = G2_NWG & 7;   // 4
  const int wgid = (xcd < r ? xcd * (q + 1) : r * (q + 1) + (xcd - r) * q) + idx;
  const int d0 = (wgid % 49) * 128;
  const int e0 = (wgid / 49) * 64;

  const int t = threadIdx.x;
  const int wave = t >> 6;
  const int lane = t & 63;
  const int l15 = lane & 15;
  const int lq = lane >> 4;
  const int wr = wave >> 1;
  const int wc = wave & 1;

  const int R0 = t >> 3;
  const int cst = t & 7;
  const int cl = cst ^ (R0 & 7);
  const short* asrc[4];
#pragma unroll
  for (int rr = 0; rr < 4; ++rr) {
    int er = e0 + R0 + (rr & 1) * 32;
    if (er >= E_NUM) er = E_NUM - 1;
    const int grow = er + (rr >> 1) * E_NUM;
    asrc[rr] = hgp + (size_t)(cl >> 2) * (M1 * 32) + (size_t)grow * 32 + (cl & 3) * 8;
  }

  const short* bbase = P2 + (size_t)(d0 + wc * 64 + l15) * 32 + lq * 8;
  const int asw = l15 & 7;

  f32x4 acc[2][2][4];
#pragma unroll
  for (int h = 0; h < 2; ++h)
#pragma unroll
    for (int m = 0; m < 2; ++m)
#pragma unroll
      for (int n = 0; n < 4; ++n) acc[h][m][n] = (f32x4){0.f, 0.f, 0.f, 0.f};

#pragma unroll
  for (int rr = 0; rr < 4; ++rr) gll16(asrc[rr], &Als[0][t * 8 + rr * 2048]);
  __syncthreads();

  int cur = 0;
#pragma unroll
  for (int it = 0; it < 4; ++it) {
    const int nxt = cur ^ 1;
    if (it < 3) {
      const size_t ko = (size_t)(it + 1) * 2 * (M1 * 32);
#pragma unroll
      for (int rr = 0; rr < 4; ++rr) gll16(asrc[rr] + ko, &Als[nxt][t * 8 + rr * 2048]);
    }
    bf16x8 bq[2][4];
#pragma unroll
    for (int ks = 0; ks < 2; ++ks)
#pragma unroll
      for (int n = 0; n < 4; ++n)
        bq[ks][n] = ld_frag(bbase + (size_t)(it * 2 + ks) * (D_DIM * 32) + n * 512);

    bf16x8 af[2][2][2];
#pragma unroll
    for (int h = 0; h < 2; ++h)
#pragma unroll
      for (int m = 0; m < 2; ++m)
#pragma unroll
        for (int ks = 0; ks < 2; ++ks) {
          const int R = h * 64 + wr * 32 + m * 16 + l15;
          af[h][m][ks] = ld_frag(&Als[cur][R * 64 + (((ks * 4 + lq) ^ asw) * 8)]);
        }
#pragma unroll
    for (int ks = 0; ks < 2; ++ks)
#pragma unroll
      for (int h = 0; h < 2; ++h)
#pragma unroll
        for (int m = 0; m < 2; ++m)
#pragma unroll
          for (int n = 0; n < 4; ++n)
            acc[h][m][n] = __builtin_amdgcn_mfma_f32_16x16x32_bf16(
                af[h][m][ks], bq[ks][n], acc[h][m][n], 0, 0, 0);
    __syncthreads();
    cur = nxt;
  }

#pragma unroll
  for (int n = 0; n < 4; ++n) {
    const int col = d0 + wc * 64 + n * 16 + l15;
    const float b2v = b2[col];
#pragma unroll
    for (int m = 0; m < 2; ++m) {
#pragma unroll
      for (int i = 0; i < 4; ++i) {
        const int e = e0 + wr * 32 + m * 16 + lq * 4 + i;
        if (e < E_NUM) {
          out[(size_t)e * D_DIM + col] =
              silu_f(acc[0][m][n][i] + b2v) + silu_f(acc[1][m][n][i] + b2v);
        }
      }
    }
  }
}

extern "C" void kernel_launch(void* const* d_in, const int* in_sizes, int n_in,
                              void* d_out, int out_size, void* d_ws, size_t ws_size,
                              hipStream_t stream) {
  const float* node_embed = (const float*)d_in[0];
  const float* x_edge_c = (const float*)d_in[1];
  const float* ori = (const float*)d_in[2];
  const float* W1 = (const float*)d_in[3];
  const float* b1 = (const float*)d_in[4];
  const float* W2 = (const float*)d_in[5];
  const float* b2 = (const float*)d_in[6];
  float* out_p = (float*)d_out;

  char* ws = (char*)d_ws;
  short* P1 = (short*)ws;                   // [196][256][32] bf16 = 3,211,264 B
  short* P2 = (short*)(ws + 3211264);       // [8][6272][32] bf16 = 3,211,264 B
  short* hgp = (short*)(ws + 2 * 3211264);  // [8][24000][32] bf16 = 12,288,000 B

  pack_both<<<dim3(392), 256, 0, stream>>>(W1, P1, W2, P2);

  gemm1_kernel<<<dim3(M1 / 32), 256, 0, stream>>>(node_embed, ori, x_edge_c, P1, b1, hgp);

  gemm2_kernel<<<dim3(G2_NWG), 256, 0, stream>>>(hgp, P2, b2, out_p);
}